// Round 8
// baseline (1909.314 us; speedup 1.0000x reference)
//
#include <hip/hip_runtime.h>
#include <hip/hip_fp16.h>
#include <math.h>

// NODE_DIM=3, EMBED=16
#define ND 3
#define EM 16
#define BQ 512        // nodes per bucket (power of 2)
#define BQ_SH 9
#define MAXB 1024     // max buckets => supports N <= 524288
#define CHK 8192      // edges per edge_bin block (32 per thread)
#define COLS 12288    // LDS staging bound (mean bucket edges ~8192, +45 sigma)
// packed pair: (dst & 511) << 23 | src   (requires src < 2^23)
#define P_SH 23
#define PMASK ((1u << P_SH) - 1)
// src ranges for phase-locked conv: 8 ranges of 65536 nodes (2MB fp16 z each)
#define RSH 16
#define NRANGE 8

__device__ __forceinline__ float sp(float x) {
    // jax.nn.softplus = max(x,0) + log1p(exp(-|x|))
    return fmaxf(x, 0.0f) + log1pf(expf(-fabsf(x)));
}

// Kernel 0: zero bucket counters.
__global__ __launch_bounds__(1024) void bucket_zero(int* __restrict__ bcnt)
{
    bcnt[threadIdx.x] = 0;
}

// Kernel A: bucket histogram of dst (bucket = dst >> 9).
__global__ __launch_bounds__(256) void bucket_count(
    const int* __restrict__ ei, int* __restrict__ bcnt, int E, int NB)
{
    __shared__ int h[MAXB];
    int t = threadIdx.x;
    for (int i = t; i < MAXB; i += 256) h[i] = 0;
    __syncthreads();
    const int* dp = ei + (size_t)E;
    for (int e = blockIdx.x * 256 + t; e < E; e += gridDim.x * 256)
        atomicAdd(&h[((unsigned)dp[e]) >> BQ_SH], 1);
    __syncthreads();
    for (int i = t; i < NB; i += 256) {
        int v = h[i];
        if (v) atomicAdd(&bcnt[i], v);
    }
}

// Kernel B: exclusive scan of bucket counts (NB <= 1024) -> gbase, gcur.
__global__ __launch_bounds__(1024) void bucket_scan(
    const int* __restrict__ bcnt, int* __restrict__ gbase,
    int* __restrict__ gcur, int NB)
{
    __shared__ int sd[1024];
    int t = threadIdx.x;
    int v = (t < NB) ? bcnt[t] : 0;
    sd[t] = v;
    __syncthreads();
    for (int off = 1; off < 1024; off <<= 1) {
        int add = (t >= off) ? sd[t - off] : 0;
        __syncthreads();
        sd[t] += add;
        __syncthreads();
    }
    if (t < NB) { int ex = sd[t] - v; gbase[t] = ex; gcur[t] = ex; }
}

// Kernel C: bin edges into bucket-contiguous packed-pair runs (LDS-sorted
// per chunk so global writes are in-order & coalesced). Unchanged.
__global__ __launch_bounds__(256) void edge_bin(
    const int* __restrict__ ei, int* __restrict__ gcur,
    unsigned int* __restrict__ pairs, int E)
{
    __shared__ int lcnt[MAXB];
    __shared__ int lbase[MAXB];
    __shared__ int sbase[MAXB];
    __shared__ unsigned int stage[CHK];
    __shared__ unsigned short bid[CHK];
    __shared__ int sd[256];
    int t = threadIdx.x;
    int c0 = blockIdx.x * CHK;
    int cntT = min(CHK, E - c0);
    for (int i = t; i < MAXB; i += 256) lcnt[i] = 0;
    __syncthreads();
    const int* dp = ei + (size_t)E;
    int dreg[32];
#pragma unroll
    for (int it = 0; it < 32; it++) {
        int e = c0 + it * 256 + t;
        dreg[it] = (e < E) ? dp[e] : 0;
        if (e < E) atomicAdd(&lcnt[((unsigned)dreg[it]) >> BQ_SH], 1);
    }
    __syncthreads();
    int b4 = t * 4;
    int h0 = lcnt[b4], h1 = lcnt[b4 + 1], h2 = lcnt[b4 + 2], h3 = lcnt[b4 + 3];
    int s4 = h0 + h1 + h2 + h3;
    sd[t] = s4;
    __syncthreads();
    for (int off = 1; off < 256; off <<= 1) {
        int add = (t >= off) ? sd[t - off] : 0;
        __syncthreads();
        sd[t] += add;
        __syncthreads();
    }
    int ex = sd[t] - s4;
    lbase[b4]     = ex;
    lbase[b4 + 1] = ex + h0;
    lbase[b4 + 2] = ex + h0 + h1;
    lbase[b4 + 3] = ex + h0 + h1 + h2;
    sbase[b4]     = h0 ? atomicAdd(&gcur[b4], h0)     : 0;
    sbase[b4 + 1] = h1 ? atomicAdd(&gcur[b4 + 1], h1) : 0;
    sbase[b4 + 2] = h2 ? atomicAdd(&gcur[b4 + 2], h2) : 0;
    sbase[b4 + 3] = h3 ? atomicAdd(&gcur[b4 + 3], h3) : 0;
    lcnt[b4] = 0; lcnt[b4 + 1] = 0; lcnt[b4 + 2] = 0; lcnt[b4 + 3] = 0;
    __syncthreads();
#pragma unroll
    for (int it = 0; it < 32; it++) {
        int e = c0 + it * 256 + t;
        if (e < E) {
            int d = dreg[it];
            unsigned b = ((unsigned)d) >> BQ_SH;
            int s = ei[e];
            int pos = lbase[b] + atomicAdd(&lcnt[b], 1);
            stage[pos] = ((unsigned)(d & (BQ - 1)) << P_SH) | (unsigned)s;
            bid[pos] = (unsigned short)b;
        }
    }
    __syncthreads();
    for (int i = t; i < cntT; i += 256) {
        unsigned b = bid[i];
        pairs[sbase[b] + (i - lbase[b])] = stage[i];
    }
}

// Kernel D (fused): per-bucket range-major edge build + dinv/rc + node init.
// One block per bucket:
//  - histogram edges by src-range (8 counters) and by dst-node (deg)
//  - scan 8 -> per-range bases; write rb8[b*8+r] (conv phase boundaries)
//  - scatter pairs into LDS staging ordered by range (within-range order free,
//    each edge carries its ldst in the packed word)
//  - flush: compute w = |pos[dst]-pos[src]| (posS in LDS, pos[src] gathered),
//    write cw2 = {packed, w} fully coalesced; accumulate wsum
//  - epilogue: dinv = rsqrt(1+wsum), rc = 1/(deg+1), and the fused node_init:
//    zh1 = fp16(dinv * (softplus(pos@Wi+bi) @ Wg1))
__global__ __launch_bounds__(256) void bucket_csr_init(
    const unsigned int* __restrict__ pairs, const int* __restrict__ gbase,
    const int* __restrict__ bcnt, const float* __restrict__ pos,
    const float* __restrict__ W_init, const float* __restrict__ b_init,
    const float* __restrict__ W_g1,
    int* __restrict__ rb8, int2* __restrict__ cw2,
    float* __restrict__ dinv, float* __restrict__ rcarr,
    __half2* __restrict__ zh1, int N, int NB)
{
    __shared__ float posS[BQ * 3];
    __shared__ unsigned int stg[COLS];
    __shared__ float wsum[BQ];
    __shared__ int dcnt[BQ];
    __shared__ int r8cnt[NRANGE];
    __shared__ int r8cur[NRANGE];
    __shared__ float sWi[ND * EM];
    __shared__ float sbi[EM];
    __shared__ float sW1[EM * EM];
    int b = blockIdx.x, t = threadIdx.x;
    int lo = b << BQ_SH;
    int hi = min(lo + BQ, N);
    int nloc = hi - lo;
    int r0 = gbase[b];
    int cntE = bcnt[b];
    if (t < ND * EM) sWi[t] = W_init[t];
    if (t < EM)      sbi[t] = b_init[t];
    sW1[t] = W_g1[t];
    for (int i = t; i < 3 * nloc; i += 256) posS[i] = pos[(size_t)lo * 3 + i];
    wsum[2 * t] = 0.0f; wsum[2 * t + 1] = 0.0f;
    dcnt[2 * t] = 0;    dcnt[2 * t + 1] = 0;
    if (t < NRANGE) r8cnt[t] = 0;
    __syncthreads();
    // pass 1: histograms
    for (int i = t; i < cntE; i += 256) {
        unsigned p = pairs[r0 + i];
        atomicAdd(&r8cnt[(p & PMASK) >> RSH], 1);
        atomicAdd(&dcnt[p >> P_SH], 1);
    }
    __syncthreads();
    if (t == 0) {
        int run = 0;
        for (int r = 0; r < NRANGE; r++) {
            int v = r8cnt[r];
            r8cur[r] = run;
            rb8[b * NRANGE + r] = r0 + run;
            run += v;
        }
    }
    __syncthreads();
    bool fit = (cntE <= COLS);
    if (fit) {
        for (int i = t; i < cntE; i += 256) {
            unsigned p = pairs[r0 + i];
            int slot = atomicAdd(&r8cur[(p & PMASK) >> RSH], 1);
            stg[slot] = p;
        }
        __syncthreads();
        for (int i = t; i < cntE; i += 256) {
            unsigned p = stg[i];
            int ldst = (int)(p >> P_SH);
            int src  = (int)(p & PMASK);
            float dx = posS[ldst * 3 + 0] - pos[(size_t)src * 3 + 0];
            float dy = posS[ldst * 3 + 1] - pos[(size_t)src * 3 + 1];
            float dz = posS[ldst * 3 + 2] - pos[(size_t)src * 3 + 2];
            float w = sqrtf(fmaf(dx, dx, fmaf(dy, dy, dz * dz)));
            cw2[r0 + i] = make_int2((int)p, __float_as_int(w));
            atomicAdd(&wsum[ldst], w);
        }
    } else {
        // overflow fallback (practically unreachable)
        for (int i = t; i < cntE; i += 256) {
            unsigned p = pairs[r0 + i];
            int ldst = (int)(p >> P_SH);
            int src  = (int)(p & PMASK);
            int slot = atomicAdd(&r8cur[(p & PMASK) >> RSH], 1);
            float dx = posS[ldst * 3 + 0] - pos[(size_t)src * 3 + 0];
            float dy = posS[ldst * 3 + 1] - pos[(size_t)src * 3 + 1];
            float dz = posS[ldst * 3 + 2] - pos[(size_t)src * 3 + 2];
            float w = sqrtf(fmaf(dx, dx, fmaf(dy, dy, dz * dz)));
            cw2[r0 + slot] = make_int2((int)p, __float_as_int(w));
            atomicAdd(&wsum[ldst], w);
        }
    }
    __syncthreads();
    // epilogue: dinv, rc, fused node_init -> zh1
    for (int l = t; l < nloc; l += 256) {
        int n = lo + l;
        float di = rsqrtf(1.0f + wsum[l]);
        dinv[n] = di;
        rcarr[n] = 1.0f / (float)(dcnt[l] + 1);
        float p0 = posS[l * 3 + 0];
        float p1 = posS[l * 3 + 1];
        float p2 = posS[l * 3 + 2];
        float x0[EM];
#pragma unroll
        for (int j = 0; j < EM; j++) {
            float h = fmaf(p0, sWi[0 * EM + j],
                      fmaf(p1, sWi[1 * EM + j],
                      fmaf(p2, sWi[2 * EM + j], sbi[j])));
            x0[j] = sp(h);
        }
        __half2* zo = zh1 + (size_t)n * 8;
#pragma unroll
        for (int k = 0; k < 8; k++) {
            float ax = 0.0f, ay = 0.0f;
#pragma unroll
            for (int j = 0; j < EM; j++) {
                ax = fmaf(x0[j], sW1[j * EM + 2 * k], ax);
                ay = fmaf(x0[j], sW1[j * EM + 2 * k + 1], ay);
            }
            zo[k] = __float22half2_rn(make_float2(ax * di, ay * di));
        }
    }
}

// Kernel E (x2): phase-locked GCN-mean layer. One block per bucket, LDS f32
// accumulators acc[512][18]; 977 blocks all co-resident (4/CU @ ~39KB LDS) so
// blocks sweep src-ranges r=0..7 in natural lockstep: the z gather working
// set at any instant is one 2MB range window per XCD (L2-resident).
// Per edge: 8-lane group, coalesced cw2 read, shuffle, z gather (L2-hot),
// 2 LDS f32 atomicAdds into the dst node's acc row.
// Epilogue: x = sp((acc+self)*di*rc + b); mode 1: zout = fp16((x@W)*di);
// mode 2: fused head y = sp(x@P1+b1), out = (y@P2+b2)/sig.
__global__ __launch_bounds__(256) void conv_p(
    const int* __restrict__ rb8, const int* __restrict__ gbase,
    const int* __restrict__ bcnt, const int2* __restrict__ cw2,
    const float* __restrict__ dinv, const float* __restrict__ rcarr,
    const __half2* __restrict__ zin, const float* __restrict__ bconv,
    const float* __restrict__ W,
    const float* __restrict__ P1, const float* __restrict__ b1,
    const float* __restrict__ P2, const float* __restrict__ b2,
    const float* __restrict__ sig,
    __half2* __restrict__ zout, float* __restrict__ out,
    int N, int mode)
{
    __shared__ float acc[BQ][EM + 2];   // stride 18: bank-rotating, 8B-aligned
    __shared__ float sW[EM * EM];
    __shared__ float sb[EM];
    __shared__ float sP1[EM * EM];
    __shared__ float sb1[EM];
    __shared__ float sP2[EM * ND];
    __shared__ float sb2[ND];
    __shared__ int rbL[NRANGE + 1];
    int b = blockIdx.x, t = threadIdx.x;
    int lo = b << BQ_SH;
    if (mode == 1) {
        sW[t] = W[t];
    } else {
        sP1[t] = P1[t];
        if (t < EM)      sb1[t] = b1[t];
        if (t < EM * ND) sP2[t] = P2[t];
        if (t < ND)      sb2[t] = b2[t];
    }
    if (t < EM) sb[t] = bconv[t];
    if (t < NRANGE) rbL[t] = rb8[b * NRANGE + t];
    if (t == NRANGE) rbL[NRANGE] = gbase[b] + bcnt[b];
    float* ap = &acc[0][0];
    for (int i = t; i < BQ * (EM + 2); i += 256) ap[i] = 0.0f;
    __syncthreads();

    int g = t >> 3, c = t & 7;          // 32 groups x 8 lanes
    for (int r = 0; r < NRANGE; r++) {
        int ee = rbL[r + 1];
        for (int e0 = rbL[r] + g * 8; e0 < ee; e0 += 32 * 8) {
            int2 cwv = (e0 + c < ee) ? cw2[e0 + c] : make_int2(0, 0);
            unsigned pk[8]; float wv[8];
#pragma unroll
            for (int k = 0; k < 8; k++) {
                pk[k] = (unsigned)__shfl(cwv.x, k, 8);
                wv[k] = __int_as_float(__shfl(cwv.y, k, 8));
            }
            __half2 zz[8];
#pragma unroll
            for (int k = 0; k < 8; k++)
                zz[k] = zin[(size_t)(pk[k] & PMASK) * 8 + c];
#pragma unroll
            for (int k = 0; k < 8; k++) {
                float2 z = __half22float2(zz[k]);
                int nl = (int)(pk[k] >> P_SH);
                atomicAdd(&acc[nl][2 * c],     wv[k] * z.x);
                atomicAdd(&acc[nl][2 * c + 1], wv[k] * z.y);
            }
        }
    }
    __syncthreads();
    // finish x per node, store back into acc (groups own disjoint rows)
    for (int j = 0; j < 16; j++) {
        int nl = j * 32 + g;
        int n = lo + nl;
        if (n < N) {
            float ax = acc[nl][2 * c], ay = acc[nl][2 * c + 1];
            float2 s = __half22float2(zin[(size_t)n * 8 + c]);
            float di = dinv[n], rc = rcarr[n];
            acc[nl][2 * c]     = sp(fmaf((ax + s.x) * di, rc, sb[2 * c]));
            acc[nl][2 * c + 1] = sp(fmaf((ay + s.y) * di, rc, sb[2 * c + 1]));
        }
    }
    __syncthreads();
    // channel-mix epilogue
    for (int j = 0; j < 16; j++) {
        int nl = j * 32 + g;
        int n = lo + nl;
        if (n >= N) continue;
        if (mode == 1) {
            float di = dinv[n];
            float ax = 0.0f, ay = 0.0f;
#pragma unroll
            for (int jj = 0; jj < EM; jj++) {
                float v = acc[nl][jj];
                ax = fmaf(v, sW[jj * EM + 2 * c], ax);
                ay = fmaf(v, sW[jj * EM + 2 * c + 1], ay);
            }
            zout[(size_t)n * 8 + c] =
                __float22half2_rn(make_float2(ax * di, ay * di));
        } else {
            float ax = sb1[2 * c], ay = sb1[2 * c + 1];
#pragma unroll
            for (int jj = 0; jj < EM; jj++) {
                float v = acc[nl][jj];
                ax = fmaf(v, sP1[jj * EM + 2 * c], ax);
                ay = fmaf(v, sP1[jj * EM + 2 * c + 1], ay);
            }
            // write y over own row; wave-synchronous ds order makes the
            // preceding reads of all lanes complete before any write
            acc[nl][2 * c]     = sp(ax);
            acc[nl][2 * c + 1] = sp(ay);
            if (c < ND) {
                float o = sb2[c];
#pragma unroll
                for (int jj = 0; jj < EM; jj++)
                    o = fmaf(acc[nl][jj], sP2[jj * ND + c], o);
                out[(size_t)n * ND + c] = o / sig[n];
            }
        }
    }
}

extern "C" void kernel_launch(void* const* d_in, const int* in_sizes, int n_in,
                              void* d_out, int out_size, void* d_ws, size_t ws_size,
                              hipStream_t stream) {
    const float* pos    = (const float*)d_in[0];
    const float* sig    = (const float*)d_in[1];
    const int*   ei     = (const int*)d_in[2];
    const float* W_init = (const float*)d_in[4];
    const float* b_init = (const float*)d_in[5];
    const float* W_g1   = (const float*)d_in[6];
    const float* b_g1   = (const float*)d_in[7];
    const float* W_g2   = (const float*)d_in[8];
    const float* b_g2   = (const float*)d_in[9];
    const float* W_p1   = (const float*)d_in[10];
    const float* b_p1   = (const float*)d_in[11];
    const float* W_p2   = (const float*)d_in[12];
    const float* b_p2   = (const float*)d_in[13];
    float* out = (float*)d_out;

    int N = in_sizes[0] / ND;
    int E = in_sizes[2] / 2;
    size_t Ns = (size_t)N, Es = (size_t)E;
    int NB = (N + BQ - 1) >> BQ_SH;   // <= MAXB for N <= 524288

    // Workspace layout (4B elements):
    // bcnt[1024] | gbase[1024] | gcur[1024] | rb8[8*MAXB] | dinv[N] | rc[N]
    //   | cw2[E] (int2) | pairs[E] (u32) | zh1[8N] (half2)
    // zh2 (8N half2 = 16MB) aliases pairs (dead after bucket_csr_init).
    int* bcnt  = (int*)d_ws;
    int* gbase = bcnt + 1024;
    int* gcur  = gbase + 1024;
    int* rb8   = gcur + 1024;
    float* dinv  = (float*)(rb8 + 8 * MAXB);
    float* rcarr = dinv + Ns;
    size_t off = 3 * 1024 + 8 * MAXB + 2 * Ns;
    off = (off + 1) & ~(size_t)1;           // 8B align for int2
    int2* cw2 = (int2*)((int*)d_ws + off);
    unsigned int* pairs = (unsigned int*)(cw2 + Es);
    __half2* zh2 = (__half2*)pairs;
    __half2* zh1 = (__half2*)(pairs + Es);

    int nbBin = (E + CHK - 1) / CHK;

    bucket_zero<<<1, 1024, 0, stream>>>(bcnt);
    bucket_count<<<1024, 256, 0, stream>>>(ei, bcnt, E, NB);
    bucket_scan<<<1, 1024, 0, stream>>>(bcnt, gbase, gcur, NB);
    edge_bin<<<nbBin, 256, 0, stream>>>(ei, gcur, pairs, E);
    bucket_csr_init<<<NB, 256, 0, stream>>>(pairs, gbase, bcnt, pos,
        W_init, b_init, W_g1, rb8, cw2, dinv, rcarr, zh1, N, NB);
    conv_p<<<NB, 256, 0, stream>>>(rb8, gbase, bcnt, cw2, dinv, rcarr,
        zh1, b_g1, W_g2, W_p1, b_p1, W_p2, b_p2, sig, zh2, out, N, 1);
    conv_p<<<NB, 256, 0, stream>>>(rb8, gbase, bcnt, cw2, dinv, rcarr,
        zh2, b_g2, W_g2, W_p1, b_p1, W_p2, b_p2, sig, zh2, out, N, 2);
}

// Round 9
// 786.286 us; speedup vs baseline: 2.4283x; 2.4283x over previous
//
#include <hip/hip_runtime.h>
#include <hip/hip_fp16.h>
#include <math.h>

// NODE_DIM=3, EMBED=16
#define ND 3
#define EM 16
#define BQ 512        // nodes per bucket (power of 2)
#define BQ_SH 9
#define MAXB 1024     // max buckets => supports N <= 524288
#define CHK 8192      // edges per edge_bin block (32 per thread)
#define COLS 12288    // LDS staging bound (mean bucket edges ~8192, +45 sigma)
// packed pair: (dst & 511) << 23 | src   (requires src < 2^23)
#define P_SH 23
#define PMASK ((1u << P_SH) - 1)

__device__ __forceinline__ float sp(float x) {
    // jax.nn.softplus = max(x,0) + log1p(exp(-|x|))
    return fmaxf(x, 0.0f) + log1pf(expf(-fabsf(x)));
}

// Kernel 0: zero bucket counters.
__global__ __launch_bounds__(1024) void bucket_zero(int* __restrict__ bcnt)
{
    bcnt[threadIdx.x] = 0;
}

// Kernel A: bucket histogram of dst (bucket = dst >> 9).
__global__ __launch_bounds__(256) void bucket_count(
    const int* __restrict__ ei, int* __restrict__ bcnt, int E, int NB)
{
    __shared__ int h[MAXB];
    int t = threadIdx.x;
    for (int i = t; i < MAXB; i += 256) h[i] = 0;
    __syncthreads();
    const int* dp = ei + (size_t)E;
    for (int e = blockIdx.x * 256 + t; e < E; e += gridDim.x * 256)
        atomicAdd(&h[((unsigned)dp[e]) >> BQ_SH], 1);
    __syncthreads();
    for (int i = t; i < NB; i += 256) {
        int v = h[i];
        if (v) atomicAdd(&bcnt[i], v);
    }
}

// Kernel B: exclusive scan of bucket counts (NB <= 1024) -> gbase, gcur.
__global__ __launch_bounds__(1024) void bucket_scan(
    const int* __restrict__ bcnt, int* __restrict__ gbase,
    int* __restrict__ gcur, int NB)
{
    __shared__ int sd[1024];
    int t = threadIdx.x;
    int v = (t < NB) ? bcnt[t] : 0;
    sd[t] = v;
    __syncthreads();
    for (int off = 1; off < 1024; off <<= 1) {
        int add = (t >= off) ? sd[t - off] : 0;
        __syncthreads();
        sd[t] += add;
        __syncthreads();
    }
    if (t < NB) { int ex = sd[t] - v; gbase[t] = ex; gcur[t] = ex; }
}

// Kernel C: bin edges into bucket-contiguous packed-pair runs (LDS-sorted
// per chunk so global writes are in-order & coalesced).
__global__ __launch_bounds__(256) void edge_bin(
    const int* __restrict__ ei, int* __restrict__ gcur,
    unsigned int* __restrict__ pairs, int E)
{
    __shared__ int lcnt[MAXB];
    __shared__ int lbase[MAXB];
    __shared__ int sbase[MAXB];
    __shared__ unsigned int stage[CHK];
    __shared__ unsigned short bid[CHK];
    __shared__ int sd[256];
    int t = threadIdx.x;
    int c0 = blockIdx.x * CHK;
    int cntT = min(CHK, E - c0);
    for (int i = t; i < MAXB; i += 256) lcnt[i] = 0;
    __syncthreads();
    const int* dp = ei + (size_t)E;
    int dreg[32];
#pragma unroll
    for (int it = 0; it < 32; it++) {
        int e = c0 + it * 256 + t;
        dreg[it] = (e < E) ? dp[e] : 0;
        if (e < E) atomicAdd(&lcnt[((unsigned)dreg[it]) >> BQ_SH], 1);
    }
    __syncthreads();
    int b4 = t * 4;
    int h0 = lcnt[b4], h1 = lcnt[b4 + 1], h2 = lcnt[b4 + 2], h3 = lcnt[b4 + 3];
    int s4 = h0 + h1 + h2 + h3;
    sd[t] = s4;
    __syncthreads();
    for (int off = 1; off < 256; off <<= 1) {
        int add = (t >= off) ? sd[t - off] : 0;
        __syncthreads();
        sd[t] += add;
        __syncthreads();
    }
    int ex = sd[t] - s4;
    lbase[b4]     = ex;
    lbase[b4 + 1] = ex + h0;
    lbase[b4 + 2] = ex + h0 + h1;
    lbase[b4 + 3] = ex + h0 + h1 + h2;
    sbase[b4]     = h0 ? atomicAdd(&gcur[b4], h0)     : 0;
    sbase[b4 + 1] = h1 ? atomicAdd(&gcur[b4 + 1], h1) : 0;
    sbase[b4 + 2] = h2 ? atomicAdd(&gcur[b4 + 2], h2) : 0;
    sbase[b4 + 3] = h3 ? atomicAdd(&gcur[b4 + 3], h3) : 0;
    lcnt[b4] = 0; lcnt[b4 + 1] = 0; lcnt[b4 + 2] = 0; lcnt[b4 + 3] = 0;
    __syncthreads();
#pragma unroll
    for (int it = 0; it < 32; it++) {
        int e = c0 + it * 256 + t;
        if (e < E) {
            int d = dreg[it];
            unsigned b = ((unsigned)d) >> BQ_SH;
            int s = ei[e];
            int pos = lbase[b] + atomicAdd(&lcnt[b], 1);
            stage[pos] = ((unsigned)(d & (BQ - 1)) << P_SH) | (unsigned)s;
            bid[pos] = (unsigned short)b;
        }
    }
    __syncthreads();
    for (int i = t; i < cntT; i += 256) {
        unsigned b = bid[i];
        pairs[sbase[b] + (i - lbase[b])] = stage[i];
    }
}

// Kernel D (fused): per-bucket CSR build + edge weights + dinv + node_init.
// One block per bucket (512 nodes, ~8192 edges):
//  - pos[dst-bucket] staged in LDS; per-node histogram -> scan -> rowptr
//  - scatter packed pairs into LDS staging (CSR order)
//  - flush: gather pos[src], w = |pos[dst]-pos[src]|, write cw={src,w}
//    fully coalesced; accumulate per-node wsum
//  - epilogue: dinv = rsqrt(1+wsum); fused node_init:
//    zh1 = fp16(dinv * (softplus(pos@Wi+bi) @ Wg1))  (pos from LDS)
__global__ __launch_bounds__(256) void bucket_csr_init(
    const unsigned int* __restrict__ pairs, const int* __restrict__ gbase,
    const int* __restrict__ bcnt, const float* __restrict__ pos,
    const float* __restrict__ W_init, const float* __restrict__ b_init,
    const float* __restrict__ W_g1,
    int* __restrict__ rowptr, int2* __restrict__ cw,
    float* __restrict__ dinv, __half2* __restrict__ zh1, int N, int NB)
{
    __shared__ int ncnt[BQ];
    __shared__ int ncur[BQ];
    __shared__ float wsum[BQ];
    __shared__ int sd[256];
    __shared__ unsigned int stg[COLS];
    __shared__ float posS[BQ * 3];
    __shared__ float sWi[ND * EM];
    __shared__ float sbi[EM];
    __shared__ float sW1[EM * EM];
    int b = blockIdx.x;
    int t = threadIdx.x;
    int lo = b << BQ_SH;
    int hi = min(lo + BQ, N);
    int nloc = hi - lo;
    int r0 = gbase[b];
    int cntE = bcnt[b];
    if (t < ND * EM) sWi[t] = W_init[t];
    if (t < EM)      sbi[t] = b_init[t];
    sW1[t] = W_g1[t];
    for (int i = t; i < 3 * nloc; i += 256) posS[i] = pos[(size_t)lo * 3 + i];
    ncnt[2 * t] = 0;
    ncnt[2 * t + 1] = 0;
    wsum[2 * t] = 0.0f;
    wsum[2 * t + 1] = 0.0f;
    __syncthreads();
    for (int i = t; i < cntE; i += 256)
        atomicAdd(&ncnt[pairs[r0 + i] >> P_SH], 1);
    __syncthreads();
    // exclusive scan over 512 (2 per thread)
    int a0 = ncnt[2 * t], a1 = ncnt[2 * t + 1];
    int s2 = a0 + a1;
    sd[t] = s2;
    __syncthreads();
    for (int off = 1; off < 256; off <<= 1) {
        int add = (t >= off) ? sd[t - off] : 0;
        __syncthreads();
        sd[t] += add;
        __syncthreads();
    }
    int ex = sd[t] - s2;          // exclusive base for node 2t
    ncur[2 * t] = ex;
    ncur[2 * t + 1] = ex + a0;
    if (lo + 2 * t < hi)     rowptr[lo + 2 * t]     = r0 + ex;
    if (lo + 2 * t + 1 < hi) rowptr[lo + 2 * t + 1] = r0 + ex + a0;
    if (b == NB - 1 && t == 0) rowptr[N] = r0 + cntE;  // == E
    __syncthreads();
    bool fit = (cntE <= COLS);
    if (fit) {
        for (int i = t; i < cntE; i += 256) {
            unsigned p = pairs[r0 + i];
            int slot = atomicAdd(&ncur[p >> P_SH], 1);
            stg[slot] = p;
        }
        __syncthreads();
        for (int i = t; i < cntE; i += 256) {
            unsigned p = stg[i];
            int ldst = (int)(p >> P_SH);
            int src = (int)(p & PMASK);
            float dx = posS[ldst * 3 + 0] - pos[(size_t)src * 3 + 0];
            float dy = posS[ldst * 3 + 1] - pos[(size_t)src * 3 + 1];
            float dz = posS[ldst * 3 + 2] - pos[(size_t)src * 3 + 2];
            float d = sqrtf(fmaf(dx, dx, fmaf(dy, dy, dz * dz)));
            cw[r0 + i] = make_int2(src, __float_as_int(d));
            atomicAdd(&wsum[ldst], d);
        }
    } else {
        // overflow fallback (practically unreachable)
        for (int i = t; i < cntE; i += 256) {
            unsigned p = pairs[r0 + i];
            int ldst = (int)(p >> P_SH);
            int src = (int)(p & PMASK);
            int slot = atomicAdd(&ncur[ldst], 1);
            float dx = posS[ldst * 3 + 0] - pos[(size_t)src * 3 + 0];
            float dy = posS[ldst * 3 + 1] - pos[(size_t)src * 3 + 1];
            float dz = posS[ldst * 3 + 2] - pos[(size_t)src * 3 + 2];
            float d = sqrtf(fmaf(dx, dx, fmaf(dy, dy, dz * dz)));
            cw[r0 + slot] = make_int2(src, __float_as_int(d));
            atomicAdd(&wsum[ldst], d);
        }
    }
    __syncthreads();
    // epilogue: dinv + fused node_init -> zh1
    for (int l = t; l < nloc; l += 256) {
        int n = lo + l;
        float di = rsqrtf(1.0f + wsum[l]);
        dinv[n] = di;
        float p0 = posS[l * 3 + 0];
        float p1 = posS[l * 3 + 1];
        float p2 = posS[l * 3 + 2];
        float x0[EM];
#pragma unroll
        for (int j = 0; j < EM; j++) {
            float h = fmaf(p0, sWi[0 * EM + j],
                      fmaf(p1, sWi[1 * EM + j],
                      fmaf(p2, sWi[2 * EM + j], sbi[j])));
            x0[j] = sp(h);
        }
        __half2* zo = zh1 + (size_t)n * 8;
#pragma unroll
        for (int k = 0; k < 8; k++) {
            float ax = 0.0f, ay = 0.0f;
#pragma unroll
            for (int j = 0; j < EM; j++) {
                ax = fmaf(x0[j], sW1[j * EM + 2 * k], ax);
                ay = fmaf(x0[j], sW1[j * EM + 2 * k + 1], ay);
            }
            zo[k] = __float22half2_rn(make_float2(ax * di, ay * di));
        }
    }
}

// Kernel 6 (x2): fused GCN-mean layer on fp16 pre-scaled operand
// zh[s][c] = fp16(dinv[s]*x[s][c]). 8 lanes/node (lane = channel pair).
// Per edge per lane: one int2 cw load + one half2 z load; f32 accumulate.
// x = sp(di*acc/(deg+1)+b).
// mode 1: zout = fp16((x@W)*di)  (pre-scaled layer-2 operand).
// mode 2: fused head: y = sp(x@P1+b1); out = (y@P2+b2)/sig  (node_out gone).
__global__ __launch_bounds__(256) void gather_conv(
    const int* __restrict__ rowptr, const int2* __restrict__ cw,
    const float* __restrict__ dinv, const __half2* __restrict__ zin,
    const float* __restrict__ bconv, const float* __restrict__ W,
    const float* __restrict__ P1, const float* __restrict__ b1,
    const float* __restrict__ P2, const float* __restrict__ b2,
    const float* __restrict__ sig,
    __half2* __restrict__ zout, float* __restrict__ out, int N, int mode)
{
    __shared__ float sW[EM * EM];
    __shared__ float sP2[EM * ND];
    __shared__ float sb1[EM];
    __shared__ float sb2[ND];
    __shared__ float lx[32][EM + 1];
    int t = threadIdx.x;
    if (mode == 1) {
        sW[t] = W[t];
    } else {
        sW[t] = P1[t];
        if (t < EM)      sb1[t] = b1[t];
        if (t < EM * ND) sP2[t] = P2[t];
        if (t < ND)      sb2[t] = b2[t];
    }
    int g = t >> 3, c = t & 7;          // 32 node groups, 8 lanes each
    int n = blockIdx.x * 32 + g;

    float xx = 0.0f, xy = 0.0f;
    float di = 1.0f;
    if (n < N) {
        int start = rowptr[n], end = rowptr[n + 1];
        di = dinv[n];
        float2 zv = __half22float2(zin[(size_t)n * 8 + c]);  // self loop
        float a0x = zv.x, a0y = zv.y;
        float a1x = 0.f, a1y = 0.f, a2x = 0.f, a2y = 0.f, a3x = 0.f, a3y = 0.f;
        int j = start;
        for (; j + 3 < end; j += 4) {
            int2 e0 = cw[j], e1 = cw[j + 1], e2 = cw[j + 2], e3 = cw[j + 3];
            float2 z0 = __half22float2(zin[(size_t)e0.x * 8 + c]);
            float2 z1 = __half22float2(zin[(size_t)e1.x * 8 + c]);
            float2 z2 = __half22float2(zin[(size_t)e2.x * 8 + c]);
            float2 z3 = __half22float2(zin[(size_t)e3.x * 8 + c]);
            float w0 = __int_as_float(e0.y), w1 = __int_as_float(e1.y);
            float w2 = __int_as_float(e2.y), w3 = __int_as_float(e3.y);
            a0x = fmaf(w0, z0.x, a0x); a0y = fmaf(w0, z0.y, a0y);
            a1x = fmaf(w1, z1.x, a1x); a1y = fmaf(w1, z1.y, a1y);
            a2x = fmaf(w2, z2.x, a2x); a2y = fmaf(w2, z2.y, a2y);
            a3x = fmaf(w3, z3.x, a3x); a3y = fmaf(w3, z3.y, a3y);
        }
        for (; j < end; j++) {
            int2 e = cw[j];
            float2 zr = __half22float2(zin[(size_t)e.x * 8 + c]);
            float wv = __int_as_float(e.y);
            a0x = fmaf(wv, zr.x, a0x); a0y = fmaf(wv, zr.y, a0y);
        }
        float accx = (a0x + a1x) + (a2x + a3x);
        float accy = (a0y + a1y) + (a2y + a3y);
        float rc = 1.0f / (float)(end - start + 1);
        xx = sp(fmaf(accx * di, rc, bconv[2 * c]));
        xy = sp(fmaf(accy * di, rc, bconv[2 * c + 1]));
    }
    __syncthreads();      // sW/lx ready
    lx[g][2 * c]     = xx;
    lx[g][2 * c + 1] = xy;
    __syncthreads();
    if (n < N) {
        if (mode == 1) {
            float ax = 0.0f, ay = 0.0f;
#pragma unroll
            for (int j = 0; j < EM; j++) {
                float lj = lx[g][j];
                ax = fmaf(lj, sW[j * EM + 2 * c], ax);
                ay = fmaf(lj, sW[j * EM + 2 * c + 1], ay);
            }
            zout[(size_t)n * 8 + c] =
                __float22half2_rn(make_float2(ax * di, ay * di));
        } else {
            // fused head. y = sp(x@P1+b1): each lane computes 2 channels,
            // reading its group's full row, then overwrites its own 2 slots.
            // Wave-lockstep: all row reads (program-order earlier ds ops)
            // complete for every lane in the wave before any lane's write;
            // rows are disjoint across waves.
            float ax = sb1[2 * c], ay = sb1[2 * c + 1];
#pragma unroll
            for (int j = 0; j < EM; j++) {
                float lj = lx[g][j];
                ax = fmaf(lj, sW[j * EM + 2 * c], ax);
                ay = fmaf(lj, sW[j * EM + 2 * c + 1], ay);
            }
            lx[g][2 * c]     = sp(ax);
            lx[g][2 * c + 1] = sp(ay);
            if (c < ND) {
                float o = sb2[c];
#pragma unroll
                for (int j = 0; j < EM; j++)
                    o = fmaf(lx[g][j], sP2[j * ND + c], o);
                out[(size_t)n * ND + c] = o / sig[n];
            }
        }
    }
}

extern "C" void kernel_launch(void* const* d_in, const int* in_sizes, int n_in,
                              void* d_out, int out_size, void* d_ws, size_t ws_size,
                              hipStream_t stream) {
    const float* pos    = (const float*)d_in[0];
    const float* sig    = (const float*)d_in[1];
    const int*   ei     = (const int*)d_in[2];
    const float* W_init = (const float*)d_in[4];
    const float* b_init = (const float*)d_in[5];
    const float* W_g1   = (const float*)d_in[6];
    const float* b_g1   = (const float*)d_in[7];
    const float* W_g2   = (const float*)d_in[8];
    const float* b_g2   = (const float*)d_in[9];
    const float* W_p1   = (const float*)d_in[10];
    const float* b_p1   = (const float*)d_in[11];
    const float* W_p2   = (const float*)d_in[12];
    const float* b_p2   = (const float*)d_in[13];
    float* out = (float*)d_out;

    int N = in_sizes[0] / ND;
    int E = in_sizes[2] / 2;
    size_t Ns = (size_t)N, Es = (size_t)E;
    int NB = (N + BQ - 1) >> BQ_SH;   // <= MAXB for N <= 524288

    // Workspace layout (4B elements):
    // rowptr[N+1] | bcnt[1024] | gbase[1024] | gcur[1024] | dinv[N]
    //   | (pad 8B) cw[E] (int2) | pairs[E] (u32) | zh1[8N] (half2)
    // zh2 (8N half2 = 16MB) aliases pairs (32MB, dead after bucket_csr_init).
    int* rowptr = (int*)d_ws;
    int* bcnt   = rowptr + (Ns + 1);
    int* gbase  = bcnt + 1024;
    int* gcur   = gbase + 1024;
    float* dinv = (float*)(gcur + 1024);
    size_t off = (Ns + 1) + 3 * 1024 + Ns;
    off = (off + 1) & ~(size_t)1;           // 8B align for int2
    int2* cw = (int2*)((int*)d_ws + off);
    unsigned int* pairs = (unsigned int*)(cw + Es);
    __half2* zh2 = (__half2*)pairs;
    __half2* zh1 = (__half2*)(pairs + Es);

    int nbG2 = (N + 31) / 32;           // gather_conv: 32 nodes/block
    int nbBin = (E + CHK - 1) / CHK;

    bucket_zero<<<1, 1024, 0, stream>>>(bcnt);
    bucket_count<<<1024, 256, 0, stream>>>(ei, bcnt, E, NB);
    bucket_scan<<<1, 1024, 0, stream>>>(bcnt, gbase, gcur, NB);
    edge_bin<<<nbBin, 256, 0, stream>>>(ei, gcur, pairs, E);
    bucket_csr_init<<<NB, 256, 0, stream>>>(pairs, gbase, bcnt, pos,
        W_init, b_init, W_g1, rowptr, cw, dinv, zh1, N, NB);
    gather_conv<<<nbG2, 256, 0, stream>>>(rowptr, cw, dinv, zh1, b_g1, W_g2,
        W_p1, b_p1, W_p2, b_p2, sig, zh2, out, N, 1);
    gather_conv<<<nbG2, 256, 0, stream>>>(rowptr, cw, dinv, zh2, b_g2, W_g2,
        W_p1, b_p1, W_p2, b_p2, sig, zh2, out, N, 2);
}

// Round 10
// 666.786 us; speedup vs baseline: 2.8635x; 1.1792x over previous
//
#include <hip/hip_runtime.h>
#include <hip/hip_fp16.h>
#include <math.h>

// NODE_DIM=3, EMBED=16
#define ND 3
#define EM 16
#define BQ 512        // nodes per bucket (power of 2)
#define BQ_SH 9
#define MAXB 1024     // max buckets => supports N <= 524288
#define CHK 8192      // edges per edge_bin block (16 per thread @512)
#define COLS 12288    // LDS staging bound (mean bucket edges ~8192, +45 sigma)
// packed pair: (dst & 511) << 23 | src   (requires src < 2^23)
#define P_SH 23
#define PMASK ((1u << P_SH) - 1)

__device__ __forceinline__ float sp(float x) {
    // jax.nn.softplus = max(x,0) + log1p(exp(-|x|))
    return fmaxf(x, 0.0f) + log1pf(expf(-fabsf(x)));
}

// Kernel 0: zero bucket counters.
__global__ __launch_bounds__(1024) void bucket_zero(int* __restrict__ bcnt)
{
    bcnt[threadIdx.x] = 0;
}

// Kernel A: bucket histogram of dst (bucket = dst >> 9).
__global__ __launch_bounds__(256) void bucket_count(
    const int* __restrict__ ei, int* __restrict__ bcnt, int E, int NB)
{
    __shared__ int h[MAXB];
    int t = threadIdx.x;
    for (int i = t; i < MAXB; i += 256) h[i] = 0;
    __syncthreads();
    const int* dp = ei + (size_t)E;
    for (int e = blockIdx.x * 256 + t; e < E; e += gridDim.x * 256)
        atomicAdd(&h[((unsigned)dp[e]) >> BQ_SH], 1);
    __syncthreads();
    for (int i = t; i < NB; i += 256) {
        int v = h[i];
        if (v) atomicAdd(&bcnt[i], v);
    }
}

// Kernel B: exclusive scan of bucket counts (NB <= 1024) -> gbase, gcur.
__global__ __launch_bounds__(1024) void bucket_scan(
    const int* __restrict__ bcnt, int* __restrict__ gbase,
    int* __restrict__ gcur, int NB)
{
    __shared__ int sd[1024];
    int t = threadIdx.x;
    int v = (t < NB) ? bcnt[t] : 0;
    sd[t] = v;
    __syncthreads();
    for (int off = 1; off < 1024; off <<= 1) {
        int add = (t >= off) ? sd[t - off] : 0;
        __syncthreads();
        sd[t] += add;
        __syncthreads();
    }
    if (t < NB) { int ex = sd[t] - v; gbase[t] = ex; gcur[t] = ex; }
}

// Kernel C (512 threads): bin edges into bucket-contiguous packed-pair runs,
// LDS-sorted per chunk so global writes are in-order & coalesced.
// 512 threads (8 waves) x 2 blocks/CU = 16 waves/CU (was 8 @256).
__global__ __launch_bounds__(512) void edge_bin(
    const int* __restrict__ ei, int* __restrict__ gcur,
    unsigned int* __restrict__ pairs, int E)
{
    __shared__ int lcnt[MAXB];
    __shared__ int lbase[MAXB];
    __shared__ int sbase[MAXB];
    __shared__ unsigned int stage[CHK];
    __shared__ unsigned short bid[CHK];
    __shared__ int sd[512];
    int t = threadIdx.x;
    int c0 = blockIdx.x * CHK;
    int cntT = min(CHK, E - c0);
    for (int i = t; i < MAXB; i += 512) lcnt[i] = 0;
    __syncthreads();
    const int* dp = ei + (size_t)E;
    int dreg[16];
#pragma unroll
    for (int it = 0; it < 16; it++) {
        int e = c0 + it * 512 + t;
        dreg[it] = (e < E) ? dp[e] : 0;
        if (e < E) atomicAdd(&lcnt[((unsigned)dreg[it]) >> BQ_SH], 1);
    }
    __syncthreads();
    // exclusive scan of lcnt[1024] (2 per thread) -> lbase; reserve runs.
    int b2 = t * 2;
    int h0 = lcnt[b2], h1 = lcnt[b2 + 1];
    int s2 = h0 + h1;
    sd[t] = s2;
    __syncthreads();
    for (int off = 1; off < 512; off <<= 1) {
        int add = (t >= off) ? sd[t - off] : 0;
        __syncthreads();
        sd[t] += add;
        __syncthreads();
    }
    int ex = sd[t] - s2;
    lbase[b2]     = ex;
    lbase[b2 + 1] = ex + h0;
    sbase[b2]     = h0 ? atomicAdd(&gcur[b2], h0)     : 0;
    sbase[b2 + 1] = h1 ? atomicAdd(&gcur[b2 + 1], h1) : 0;
    lcnt[b2] = 0; lcnt[b2 + 1] = 0;
    __syncthreads();
#pragma unroll
    for (int it = 0; it < 16; it++) {
        int e = c0 + it * 512 + t;
        if (e < E) {
            int d = dreg[it];
            unsigned b = ((unsigned)d) >> BQ_SH;
            int s = ei[e];
            int pos = lbase[b] + atomicAdd(&lcnt[b], 1);
            stage[pos] = ((unsigned)(d & (BQ - 1)) << P_SH) | (unsigned)s;
            bid[pos] = (unsigned short)b;
        }
    }
    __syncthreads();
    for (int i = t; i < cntT; i += 512) {
        unsigned b = bid[i];
        pairs[sbase[b] + (i - lbase[b])] = stage[i];
    }
}

// Kernel D (512 threads, fused): per-bucket CSR build + edge weights + dinv
// + node_init. Low-VGPR epilogue: 8-lane groups, x0 exchanged via LDS lx
// (no per-thread x0[16] array -> VGPR ~70, was 216).
__global__ __launch_bounds__(512) void bucket_csr_init(
    const unsigned int* __restrict__ pairs, const int* __restrict__ gbase,
    const int* __restrict__ bcnt, const float* __restrict__ pos,
    const float* __restrict__ W_init, const float* __restrict__ b_init,
    const float* __restrict__ W_g1,
    int* __restrict__ rowptr, int2* __restrict__ cw,
    float* __restrict__ dinv, __half2* __restrict__ zh1, int N, int NB)
{
    __shared__ int ncnt[BQ];
    __shared__ int ncur[BQ];
    __shared__ float wsum[BQ];
    __shared__ int sd[512];
    __shared__ unsigned int stg[COLS];
    __shared__ float posS[BQ * 3];
    __shared__ float sWi[ND * EM];
    __shared__ float sbi[EM];
    __shared__ float sW1[EM * EM];
    __shared__ float lx[64][EM + 2];
    int b = blockIdx.x;
    int t = threadIdx.x;
    int lo = b << BQ_SH;
    int hi = min(lo + BQ, N);
    int nloc = hi - lo;
    int r0 = gbase[b];
    int cntE = bcnt[b];
    if (t < ND * EM)  sWi[t] = W_init[t];
    if (t < EM)       sbi[t] = b_init[t];
    if (t < EM * EM)  sW1[t] = W_g1[t];
    for (int i = t; i < 3 * nloc; i += 512) posS[i] = pos[(size_t)lo * 3 + i];
    ncnt[t] = 0;
    wsum[t] = 0.0f;
    __syncthreads();
    for (int i = t; i < cntE; i += 512)
        atomicAdd(&ncnt[pairs[r0 + i] >> P_SH], 1);
    __syncthreads();
    // exclusive scan over 512 (1 per thread)
    int v = ncnt[t];
    sd[t] = v;
    __syncthreads();
    for (int off = 1; off < 512; off <<= 1) {
        int add = (t >= off) ? sd[t - off] : 0;
        __syncthreads();
        sd[t] += add;
        __syncthreads();
    }
    int ex = sd[t] - v;
    ncur[t] = ex;
    if (lo + t < hi) rowptr[lo + t] = r0 + ex;
    if (b == NB - 1 && t == 0) rowptr[N] = r0 + cntE;  // == E
    __syncthreads();
    bool fit = (cntE <= COLS);
    if (fit) {
        for (int i = t; i < cntE; i += 512) {
            unsigned p = pairs[r0 + i];
            int slot = atomicAdd(&ncur[p >> P_SH], 1);
            stg[slot] = p;
        }
        __syncthreads();
        for (int i = t; i < cntE; i += 512) {
            unsigned p = stg[i];
            int ldst = (int)(p >> P_SH);
            int src = (int)(p & PMASK);
            float dx = posS[ldst * 3 + 0] - pos[(size_t)src * 3 + 0];
            float dy = posS[ldst * 3 + 1] - pos[(size_t)src * 3 + 1];
            float dz = posS[ldst * 3 + 2] - pos[(size_t)src * 3 + 2];
            float d = sqrtf(fmaf(dx, dx, fmaf(dy, dy, dz * dz)));
            cw[r0 + i] = make_int2(src, __float_as_int(d));
            atomicAdd(&wsum[ldst], d);
        }
    } else {
        // overflow fallback (practically unreachable)
        for (int i = t; i < cntE; i += 512) {
            unsigned p = pairs[r0 + i];
            int ldst = (int)(p >> P_SH);
            int src = (int)(p & PMASK);
            int slot = atomicAdd(&ncur[ldst], 1);
            float dx = posS[ldst * 3 + 0] - pos[(size_t)src * 3 + 0];
            float dy = posS[ldst * 3 + 1] - pos[(size_t)src * 3 + 1];
            float dz = posS[ldst * 3 + 2] - pos[(size_t)src * 3 + 2];
            float d = sqrtf(fmaf(dx, dx, fmaf(dy, dy, dz * dz)));
            cw[r0 + slot] = make_int2(src, __float_as_int(d));
            atomicAdd(&wsum[ldst], d);
        }
    }
    __syncthreads();
    // epilogue: dinv + fused node_init -> zh1, 8-lane groups (low VGPR).
    // lane c computes x0 channels {2c,2c+1} -> lx row (wave-internal
    // exchange, same-wave ds ordering) -> matmul pair -> zh1.
    int g = t >> 3, c = t & 7;          // 64 groups x 8 lanes
    for (int j = 0; j < BQ / 64; j++) {
        int nl = j * 64 + g;
        if (nl < nloc) {
            float p0 = posS[nl * 3 + 0];
            float p1 = posS[nl * 3 + 1];
            float p2 = posS[nl * 3 + 2];
            int k0 = 2 * c, k1 = 2 * c + 1;
            float h0 = fmaf(p0, sWi[0 * EM + k0],
                       fmaf(p1, sWi[1 * EM + k0],
                       fmaf(p2, sWi[2 * EM + k0], sbi[k0])));
            float h1 = fmaf(p0, sWi[0 * EM + k1],
                       fmaf(p1, sWi[1 * EM + k1],
                       fmaf(p2, sWi[2 * EM + k1], sbi[k1])));
            lx[g][k0] = sp(h0);
            lx[g][k1] = sp(h1);
            float di = rsqrtf(1.0f + wsum[nl]);
            int n = lo + nl;
            if (c == 0) dinv[n] = di;
            float ax = 0.0f, ay = 0.0f;
#pragma unroll
            for (int jj = 0; jj < EM; jj++) {
                float lj = lx[g][jj];
                ax = fmaf(lj, sW1[jj * EM + k0], ax);
                ay = fmaf(lj, sW1[jj * EM + k1], ay);
            }
            zh1[(size_t)n * 8 + c] =
                __float22half2_rn(make_float2(ax * di, ay * di));
        }
    }
}

// Kernel 6 (x2): fused GCN-mean layer on fp16 pre-scaled operand
// zh[s][c] = fp16(dinv[s]*x[s][c]). 8 lanes/node (lane = channel pair).
// Per edge per lane: one int2 cw load + one half2 z load; f32 accumulate.
// x = sp(di*acc/(deg+1)+b).
// mode 1: zout = fp16((x@W)*di)  (pre-scaled layer-2 operand).
// mode 2: fused head: y = sp(x@P1+b1); out = (y@P2+b2)/sig.
__global__ __launch_bounds__(256) void gather_conv(
    const int* __restrict__ rowptr, const int2* __restrict__ cw,
    const float* __restrict__ dinv, const __half2* __restrict__ zin,
    const float* __restrict__ bconv, const float* __restrict__ W,
    const float* __restrict__ P1, const float* __restrict__ b1,
    const float* __restrict__ P2, const float* __restrict__ b2,
    const float* __restrict__ sig,
    __half2* __restrict__ zout, float* __restrict__ out, int N, int mode)
{
    __shared__ float sW[EM * EM];
    __shared__ float sP2[EM * ND];
    __shared__ float sb1[EM];
    __shared__ float sb2[ND];
    __shared__ float lx[32][EM + 1];
    int t = threadIdx.x;
    if (mode == 1) {
        sW[t] = W[t];
    } else {
        sW[t] = P1[t];
        if (t < EM)      sb1[t] = b1[t];
        if (t < EM * ND) sP2[t] = P2[t];
        if (t < ND)      sb2[t] = b2[t];
    }
    int g = t >> 3, c = t & 7;          // 32 node groups, 8 lanes each
    int n = blockIdx.x * 32 + g;

    float xx = 0.0f, xy = 0.0f;
    float di = 1.0f;
    if (n < N) {
        int start = rowptr[n], end = rowptr[n + 1];
        di = dinv[n];
        float2 zv = __half22float2(zin[(size_t)n * 8 + c]);  // self loop
        float a0x = zv.x, a0y = zv.y;
        float a1x = 0.f, a1y = 0.f, a2x = 0.f, a2y = 0.f, a3x = 0.f, a3y = 0.f;
        int j = start;
        for (; j + 3 < end; j += 4) {
            int2 e0 = cw[j], e1 = cw[j + 1], e2 = cw[j + 2], e3 = cw[j + 3];
            float2 z0 = __half22float2(zin[(size_t)e0.x * 8 + c]);
            float2 z1 = __half22float2(zin[(size_t)e1.x * 8 + c]);
            float2 z2 = __half22float2(zin[(size_t)e2.x * 8 + c]);
            float2 z3 = __half22float2(zin[(size_t)e3.x * 8 + c]);
            float w0 = __int_as_float(e0.y), w1 = __int_as_float(e1.y);
            float w2 = __int_as_float(e2.y), w3 = __int_as_float(e3.y);
            a0x = fmaf(w0, z0.x, a0x); a0y = fmaf(w0, z0.y, a0y);
            a1x = fmaf(w1, z1.x, a1x); a1y = fmaf(w1, z1.y, a1y);
            a2x = fmaf(w2, z2.x, a2x); a2y = fmaf(w2, z2.y, a2y);
            a3x = fmaf(w3, z3.x, a3x); a3y = fmaf(w3, z3.y, a3y);
        }
        for (; j < end; j++) {
            int2 e = cw[j];
            float2 zr = __half22float2(zin[(size_t)e.x * 8 + c]);
            float wv = __int_as_float(e.y);
            a0x = fmaf(wv, zr.x, a0x); a0y = fmaf(wv, zr.y, a0y);
        }
        float accx = (a0x + a1x) + (a2x + a3x);
        float accy = (a0y + a1y) + (a2y + a3y);
        float rc = 1.0f / (float)(end - start + 1);
        xx = sp(fmaf(accx * di, rc, bconv[2 * c]));
        xy = sp(fmaf(accy * di, rc, bconv[2 * c + 1]));
    }
    __syncthreads();      // sW/lx ready
    lx[g][2 * c]     = xx;
    lx[g][2 * c + 1] = xy;
    __syncthreads();
    if (n < N) {
        if (mode == 1) {
            float ax = 0.0f, ay = 0.0f;
#pragma unroll
            for (int j = 0; j < EM; j++) {
                float lj = lx[g][j];
                ax = fmaf(lj, sW[j * EM + 2 * c], ax);
                ay = fmaf(lj, sW[j * EM + 2 * c + 1], ay);
            }
            zout[(size_t)n * 8 + c] =
                __float22half2_rn(make_float2(ax * di, ay * di));
        } else {
            // fused head: y = sp(x@P1+b1) over own row (wave-lockstep safe),
            // then out = (y@P2+b2)/sig.
            float ax = sb1[2 * c], ay = sb1[2 * c + 1];
#pragma unroll
            for (int j = 0; j < EM; j++) {
                float lj = lx[g][j];
                ax = fmaf(lj, sW[j * EM + 2 * c], ax);
                ay = fmaf(lj, sW[j * EM + 2 * c + 1], ay);
            }
            lx[g][2 * c]     = sp(ax);
            lx[g][2 * c + 1] = sp(ay);
            if (c < ND) {
                float o = sb2[c];
#pragma unroll
                for (int j = 0; j < EM; j++)
                    o = fmaf(lx[g][j], sP2[j * ND + c], o);
                out[(size_t)n * ND + c] = o / sig[n];
            }
        }
    }
}

extern "C" void kernel_launch(void* const* d_in, const int* in_sizes, int n_in,
                              void* d_out, int out_size, void* d_ws, size_t ws_size,
                              hipStream_t stream) {
    const float* pos    = (const float*)d_in[0];
    const float* sig    = (const float*)d_in[1];
    const int*   ei     = (const int*)d_in[2];
    const float* W_init = (const float*)d_in[4];
    const float* b_init = (const float*)d_in[5];
    const float* W_g1   = (const float*)d_in[6];
    const float* b_g1   = (const float*)d_in[7];
    const float* W_g2   = (const float*)d_in[8];
    const float* b_g2   = (const float*)d_in[9];
    const float* W_p1   = (const float*)d_in[10];
    const float* b_p1   = (const float*)d_in[11];
    const float* W_p2   = (const float*)d_in[12];
    const float* b_p2   = (const float*)d_in[13];
    float* out = (float*)d_out;

    int N = in_sizes[0] / ND;
    int E = in_sizes[2] / 2;
    size_t Ns = (size_t)N, Es = (size_t)E;
    int NB = (N + BQ - 1) >> BQ_SH;   // <= MAXB for N <= 524288

    // Workspace layout (4B elements):
    // rowptr[N+1] | bcnt[1024] | gbase[1024] | gcur[1024] | dinv[N]
    //   | (pad 8B) cw[E] (int2) | pairs[E] (u32) | zh1[8N] (half2)
    // zh2 (8N half2 = 16MB) aliases pairs (32MB, dead after bucket_csr_init).
    int* rowptr = (int*)d_ws;
    int* bcnt   = rowptr + (Ns + 1);
    int* gbase  = bcnt + 1024;
    int* gcur   = gbase + 1024;
    float* dinv = (float*)(gcur + 1024);
    size_t off = (Ns + 1) + 3 * 1024 + Ns;
    off = (off + 1) & ~(size_t)1;           // 8B align for int2
    int2* cw = (int2*)((int*)d_ws + off);
    unsigned int* pairs = (unsigned int*)(cw + Es);
    __half2* zh2 = (__half2*)pairs;
    __half2* zh1 = (__half2*)(pairs + Es);

    int nbG2 = (N + 31) / 32;           // gather_conv: 32 nodes/block
    int nbBin = (E + CHK - 1) / CHK;

    bucket_zero<<<1, 1024, 0, stream>>>(bcnt);
    bucket_count<<<1024, 256, 0, stream>>>(ei, bcnt, E, NB);
    bucket_scan<<<1, 1024, 0, stream>>>(bcnt, gbase, gcur, NB);
    edge_bin<<<nbBin, 512, 0, stream>>>(ei, gcur, pairs, E);
    bucket_csr_init<<<NB, 512, 0, stream>>>(pairs, gbase, bcnt, pos,
        W_init, b_init, W_g1, rowptr, cw, dinv, zh1, N, NB);
    gather_conv<<<nbG2, 256, 0, stream>>>(rowptr, cw, dinv, zh1, b_g1, W_g2,
        W_p1, b_p1, W_p2, b_p2, sig, zh2, out, N, 1);
    gather_conv<<<nbG2, 256, 0, stream>>>(rowptr, cw, dinv, zh2, b_g2, W_g2,
        W_p1, b_p1, W_p2, b_p2, sig, zh2, out, N, 2);
}